// Round 10
// baseline (128.444 us; speedup 1.0000x reference)
//
#include <hip/hip_runtime.h>
#include <stdint.h>

#define B_  2
#define S_  2048
#define D_  1024
#define H_  16
#define DK_ 64

using bf16x8 = __attribute__((ext_vector_type(8))) short;
using f32x4  = __attribute__((ext_vector_type(4))) float;

__device__ __forceinline__ unsigned short f2bf(float f) {
    union { float f; uint32_t u; } v; v.f = f;
    uint32_t r = v.u + 0x7FFFu + ((v.u >> 16) & 1u);
    return (unsigned short)(r >> 16);
}

// pack two f32 -> one u32 of two bf16 (low = s0), RNE in HW
__device__ __forceinline__ uint32_t cvtpk(float lo, float hi) {
    uint32_t r;
    asm("v_cvt_pk_bf16_f32 %0, %1, %2" : "=v"(r) : "v"(lo), "v"(hi));
    return r;
}
// a' = {a(0-31), b(0-31)} ; b' = {a(32-63), b(32-63)}
__device__ __forceinline__ void ps32(uint32_t& a, uint32_t& b) {
    asm volatile("v_permlane32_swap_b32 %0, %1" : "+v"(a), "+v"(b));
}
// 16-lane rows: odd rows of a <-> even rows of b
__device__ __forceinline__ void ps16(uint32_t& a, uint32_t& b) {
    asm volatile("v_permlane16_swap_b32 %0, %1" : "+v"(a), "+v"(b));
}

// async global->LDS, 16B per lane; LDS dest is wave-uniform base + lane*16
#define GLD16(G, L) __builtin_amdgcn_global_load_lds( \
    (const __attribute__((address_space(1))) void*)(const void*)(G), \
    (__attribute__((address_space(3))) void*)(void*)(L), 16, 0, 0)

// ---------------- fp32 -> bf16 convert (vectorized) ----------------
__global__ __launch_bounds__(256) void k_f32_to_bf16(const float* __restrict__ src,
                                                     unsigned short* __restrict__ dst,
                                                     int n4) {
    int i = blockIdx.x * 256 + threadIdx.x;
    if (i >= n4) return;
    float4 v = ((const float4*)src)[i];
    union { unsigned short u[4]; uint2 d; } o;
    o.u[0] = f2bf(v.x); o.u[1] = f2bf(v.y); o.u[2] = f2bf(v.z); o.u[3] = f2bf(v.w);
    ((uint2*)dst)[i] = o.d;
}

// fused 4-weight convert: grid (1024, 4)
__global__ __launch_bounds__(256) void k_wconv(
    const float* __restrict__ s0, const float* __restrict__ s1,
    const float* __restrict__ s2, const float* __restrict__ s3,
    unsigned short* __restrict__ d0, unsigned short* __restrict__ d1,
    unsigned short* __restrict__ d2, unsigned short* __restrict__ d3) {
    const int w = blockIdx.y;
    const float* s = w == 0 ? s0 : w == 1 ? s1 : w == 2 ? s2 : s3;
    unsigned short* d = w == 0 ? d0 : w == 1 ? d1 : w == 2 ? d2 : d3;
    int i = blockIdx.x * 256 + threadIdx.x;
    float4 v = ((const float4*)s)[i];
    union { unsigned short u[4]; uint2 dd; } o;
    o.u[0] = f2bf(v.x); o.u[1] = f2bf(v.y); o.u[2] = f2bf(v.z); o.u[3] = f2bf(v.w);
    ((uint2*)d)[i] = o.dd;
}

// ---------------- GEMM: C[m][n] = sum_k A[m][k] * W[n][k]  (B^T input) ------
// conflict-free XOR swizzle (both-sides) + 2-phase prefetch (round-8 proven)
template<int MODE>
__global__ __launch_bounds__(256) void k_gemm_bt(
    const unsigned short* __restrict__ A,
    const unsigned short* __restrict__ W0,
    const unsigned short* __restrict__ W1,
    const unsigned short* __restrict__ W2,
    void* __restrict__ C0, void* __restrict__ C1, void* __restrict__ C2,
    int M, int N, int K)
{
    __shared__ __align__(16) unsigned short As[2][128 * 32];
    __shared__ __align__(16) unsigned short Bs[2][128 * 32];

    const int tid  = threadIdx.x;
    const int wid  = tid >> 6, lane = tid & 63;
    const int m16  = lane & 15, g = lane >> 4;
    const int m0   = blockIdx.x * 128, n0 = blockIdx.y * 128;
    const unsigned short* Wm = blockIdx.z == 0 ? W0 : (blockIdx.z == 1 ? W1 : W2);
    void* Cm = blockIdx.z == 0 ? C0 : (blockIdx.z == 1 ? C1 : C2);

    const int wm = (wid >> 1) * 64, wn = (wid & 1) * 64;
    const int srow = lane >> 2;
    const int scol = ((lane & 3) ^ ((lane >> 3) & 3)) * 8;
    const int sw8  = (m16 >> 1) & 3;

    const f32x4 fz = {0.f, 0.f, 0.f, 0.f};
    f32x4 acc[4][4];
#pragma unroll
    for (int i = 0; i < 4; ++i)
#pragma unroll
        for (int j = 0; j < 4; ++j) acc[i][j] = fz;

#pragma unroll
    for (int c = 0; c < 2; ++c) {
        const int chunk = wid * 2 + c;
        const int row   = chunk * 16 + srow;
        GLD16(A  + (size_t)(m0 + row) * K + scol, &As[0][chunk * 512]);
        GLD16(Wm + (size_t)(n0 + row) * K + scol, &Bs[0][chunk * 512]);
    }
    __syncthreads();

    int buf = 0;
    for (int k0 = 0; k0 < K; k0 += 32) {
        if (k0 + 32 < K) {
#pragma unroll
            for (int c = 0; c < 2; ++c) {
                const int chunk = wid * 2 + c;
                const int row   = chunk * 16 + srow;
                GLD16(A  + (size_t)(m0 + row) * K + k0 + 32 + scol, &As[buf ^ 1][chunk * 512]);
                GLD16(Wm + (size_t)(n0 + row) * K + k0 + 32 + scol, &Bs[buf ^ 1][chunk * 512]);
            }
        }
        bf16x8 af[4], bf[4];
#pragma unroll
        for (int i = 0; i < 4; ++i)
            af[i] = *(const bf16x8*)(&As[buf][(wm + i * 16 + m16) * 32 + ((g ^ sw8) * 8)]);
#pragma unroll
        for (int j = 0; j < 4; ++j)
            bf[j] = *(const bf16x8*)(&Bs[buf][(wn + j * 16 + m16) * 32 + ((g ^ sw8) * 8)]);
#pragma unroll
        for (int i = 0; i < 4; ++i)
#pragma unroll
            for (int j = 0; j < 4; ++j)
                acc[i][j] = __builtin_amdgcn_mfma_f32_16x16x32_bf16(af[i], bf[j], acc[i][j], 0, 0, 0);
        __syncthreads();
        buf ^= 1;
    }

#pragma unroll
    for (int i = 0; i < 4; ++i) {
#pragma unroll
        for (int j = 0; j < 4; ++j) {
#pragma unroll
            for (int r = 0; r < 4; ++r) {
                const int row = m0 + wm + i * 16 + g * 4 + r;
                const int col = n0 + wn + j * 16 + m16;
                const float val = acc[i][j][r];
                if (MODE == 1) {
                    ((float*)Cm)[(size_t)row * N + col] = val;
                } else {
                    const int b = row >> 11, s = row & (S_ - 1);
                    const int h = col >> 6,  dk = col & (DK_ - 1);
                    size_t idx;
                    if (blockIdx.z == 2)   // V: transposed [bh][dk][s]
                        idx = ((size_t)((b * H_ + h) * DK_ + dk)) * S_ + s;
                    else                   // Q,K: [bh][s][dk]
                        idx = ((size_t)((b * H_ + h) * S_ + s)) * DK_ + dk;
                    ((unsigned short*)Cm)[idx] = f2bf(val);
                }
            }
        }
    }
}

// ---------------- RoPE in place on [bh][s][dk] bf16 buffers ----------------
__global__ __launch_bounds__(256) void k_rope_inplace(
    unsigned short* __restrict__ qh, unsigned short* __restrict__ kh,
    const int* __restrict__ tok)
{
    const int idx = blockIdx.x * 256 + threadIdx.x;
    const int c = idx & 7;
    const int s = (idx >> 3) & (S_ - 1);
    const int b = idx >> 18;
    const size_t off = (size_t)idx * 8;

    const float pos = (float)tok[b * S_ + s];
    float cs[4], sn[4];
#pragma unroll
    for (int i = 0; i < 4; ++i) {
        const int p = c * 4 + i;
        const float inv = exp2f((float)(-2 * p) * (13.287712379549449f / 64.f));
        sincosf(pos * inv, &sn[i], &cs[i]);
    }
    bf16x8 qv = *(bf16x8*)(qh + off);
    bf16x8 kv = *(bf16x8*)(kh + off);
    bf16x8 qo, ko;
#pragma unroll
    for (int i = 0; i < 4; ++i) {
        union { uint32_t u; float f; } q1{(uint32_t)(unsigned short)qv[2*i] << 16};
        union { uint32_t u; float f; } q2{(uint32_t)(unsigned short)qv[2*i+1] << 16};
        qo[2 * i]     = (short)f2bf(q1.f * cs[i] - q2.f * sn[i]);
        qo[2 * i + 1] = (short)f2bf(q1.f * sn[i] + q2.f * cs[i]);
        union { uint32_t u; float f; } k1{(uint32_t)(unsigned short)kv[2*i] << 16};
        union { uint32_t u; float f; } k2{(uint32_t)(unsigned short)kv[2*i+1] << 16};
        ko[2 * i]     = (short)f2bf(k1.f * cs[i] - k2.f * sn[i]);
        ko[2 * i + 1] = (short)f2bf(k1.f * sn[i] + k2.f * cs[i]);
    }
    *(bf16x8*)(qh + off) = qo;
    *(bf16x8*)(kh + off) = ko;
}

// ---------------- causal flash attention v8 ----------------
// v6 structure (16-row waves, 64-kv tiles, uniform fold j/31-j, permlane P)
// + T3/T4 pipeline: 3 LDS buffers, flattened 33-step loop, body =
// {vmcnt(4); s_barrier; sched_barrier; stage(u+2); compute(u)} — staged
// loads stay in flight ACROSS barriers (never drained to 0 in the loop).
// Both phases' Q frags preloaded so only staging loads circulate in vmcnt.
// 3-buffer safety: tile-u ds_reads are serviced before tile-u MFMAs issue
// (compiler lgkm waits) hence before the wave reaches barrier u+1, which
// precedes any stage(u+3) overwrite of buf[u%3].
__global__ __launch_bounds__(256, 2) void k_fattn8(
    const unsigned short* __restrict__ Q,   // [bh][s][64]
    const unsigned short* __restrict__ K,   // [bh][s][64]
    const unsigned short* __restrict__ Vt,  // [bh][64][2048]
    unsigned short* __restrict__ O)         // [b][s][1024] bf16
{
    __shared__ __align__(16) unsigned short Ks[3][64 * 64];   // 8 KB each
    __shared__ __align__(16) unsigned short Vs[3][64 * 64];   // [dv][kv]

    const int tid = threadIdx.x, wid = tid >> 6, lane = tid & 63;
    const int m16 = lane & 15, g = lane >> 4;
    const int bh = blockIdx.x & 31;
    const int j  = blockIdx.x >> 5;                     // 0..15
    const int b = bh >> 4, h = bh & 15;
    const unsigned short* Qb = Q  + (size_t)bh * S_ * DK_;
    const unsigned short* Kb = K  + (size_t)bh * S_ * DK_;
    const unsigned short* Vb = Vt + (size_t)bh * DK_ * S_;

    const int r8   = lane >> 3;          // staging row within 8-row chunk
    const int slot = (lane & 7) ^ r8;    // pre-swizzled source 16B slot
    const int ch0  = wid * 2, ch1 = wid * 2 + 1;

    const f32x4 fz = {0.f, 0.f, 0.f, 0.f};
    const float kSc = 0.125f * 1.4426950408889634f;   // 1/sqrt(DK) * log2(e)
    const int nt0 = j + 1;               // steps in phase 0 (total = 33 always)

    // Q fragments for BOTH phases, preloaded before staging
    const int qrow0 = j * 64 + wid * 16 + m16;
    const int qrow1 = (31 - j) * 64 + wid * 16 + m16;
    bf16x8 qf0[2], qf1[2];
    {
        const unsigned short* qp = Qb + (size_t)qrow0 * DK_ + g * 8;
        qf0[0] = *(const bf16x8*)(qp);
        qf0[1] = *(const bf16x8*)(qp + 32);
    }
    {
        const unsigned short* qp = Qb + (size_t)qrow1 * DK_ + g * 8;
        qf1[0] = *(const bf16x8*)(qp);
        qf1[1] = *(const bf16x8*)(qp + 32);
    }

    // prologue: stage steps 0 and 1
    {
        GLD16(Kb + (size_t)(ch0 * 8 + r8) * DK_ + slot * 8, &Ks[0][ch0 * 512]);
        GLD16(Kb + (size_t)(ch1 * 8 + r8) * DK_ + slot * 8, &Ks[0][ch1 * 512]);
        GLD16(Vb + (size_t)(ch0 * 8 + r8) * S_  + slot * 8, &Vs[0][ch0 * 512]);
        GLD16(Vb + (size_t)(ch1 * 8 + r8) * S_  + slot * 8, &Vs[0][ch1 * 512]);
        const int kv1 = (1 < nt0 ? 1 : 0) * 64;
        GLD16(Kb + (size_t)(kv1 + ch0 * 8 + r8) * DK_ + slot * 8, &Ks[1][ch0 * 512]);
        GLD16(Kb + (size_t)(kv1 + ch1 * 8 + r8) * DK_ + slot * 8, &Ks[1][ch1 * 512]);
        GLD16(Vb + (size_t)(ch0 * 8 + r8) * S_ + kv1 + slot * 8, &Vs[1][ch0 * 512]);
        GLD16(Vb + (size_t)(ch1 * 8 + r8) * S_ + kv1 + slot * 8, &Vs[1][ch1 * 512]);
    }

    f32x4 o[4];
#pragma unroll
    for (int i = 0; i < 4; ++i) o[i] = fz;
    float ps = 0.f;

    for (int u = 0; u < 33; ++u) {
        const int phase = (u >= nt0) ? 1 : 0;

        if (u == nt0) {
            // phase-0 epilogue: denominator + store q-tile j, then reset
            float s = ps;
            s += __shfl_xor(s, 16);
            s += __shfl_xor(s, 32);
            const float inv = 1.f / s;
            float lrq[4];
#pragma unroll
            for (int r = 0; r < 4; ++r)
                lrq[r] = __shfl(inv, g * 4 + r);
#pragma unroll
            for (int c2 = 0; c2 < 4; ++c2)
#pragma unroll
                for (int r = 0; r < 4; ++r) {
                    const int orow = j * 64 + wid * 16 + g * 4 + r;
                    const int ocol = h * DK_ + c2 * 16 + m16;
                    O[((size_t)(b * S_ + orow)) * D_ + ocol] = f2bf(o[c2][r] * lrq[r]);
                }
#pragma unroll
            for (int i = 0; i < 4; ++i) o[i] = fz;
            ps = 0.f;
        }

        // counted wait: stage(u) done, stage(u+1)/stage(u+2) stay in flight
        if (u < 32) asm volatile("s_waitcnt vmcnt(4)" ::: "memory");
        else        asm volatile("s_waitcnt vmcnt(0)" ::: "memory");
        __builtin_amdgcn_s_barrier();
        __builtin_amdgcn_sched_barrier(0);

        // stage step u+2 into buf[(u+2)%3] (safe: all waves done reading it)
        if (u + 2 < 33) {
            const int v2 = u + 2;
            const int kv2 = (v2 < nt0 ? v2 : v2 - nt0) * 64;
            unsigned short* kd = &Ks[(u + 2) % 3][0];
            unsigned short* vd = &Vs[(u + 2) % 3][0];
            GLD16(Kb + (size_t)(kv2 + ch0 * 8 + r8) * DK_ + slot * 8, kd + ch0 * 512);
            GLD16(Kb + (size_t)(kv2 + ch1 * 8 + r8) * DK_ + slot * 8, kd + ch1 * 512);
            GLD16(Vb + (size_t)(ch0 * 8 + r8) * S_ + kv2 + slot * 8, vd + ch0 * 512);
            GLD16(Vb + (size_t)(ch1 * 8 + r8) * S_ + kv2 + slot * 8, vd + ch1 * 512);
        }

        const int kv0 = (phase ? u - nt0 : u) * 64;
        const unsigned short* Kbuf = &Ks[u % 3][0];
        const unsigned short* Vbuf = &Vs[u % 3][0];
        const bf16x8* qf = phase ? qf1 : qf0;
        const int qrow = phase ? qrow1 : qrow0;

        // S^T = K Q^T : lane (m16,g) reg (c,r) = S[kv0+c*16+g*4+r][qrow]
        f32x4 sc[4];
        __builtin_amdgcn_s_setprio(1);
#pragma unroll
        for (int c = 0; c < 4; ++c) {
            const int row = c * 16 + m16, rr = row & 7;
            bf16x8 kf0 = *(const bf16x8*)(Kbuf + row * 64 + ((g ^ rr) << 3));
            bf16x8 kf1 = *(const bf16x8*)(Kbuf + row * 64 + (((4 + g) ^ rr) << 3));
            f32x4 z = fz;
            z = __builtin_amdgcn_mfma_f32_16x16x32_bf16(kf0, qf[0], z, 0, 0, 0);
            z = __builtin_amdgcn_mfma_f32_16x16x32_bf16(kf1, qf[1], z, 0, 0, 0);
            sc[c] = z;
        }
        __builtin_amdgcn_s_setprio(0);

        // V B-frags hoisted above softmax (latency hides under exp/permlane)
        bf16x8 vf[2][4];
#pragma unroll
        for (int c2 = 0; c2 < 4; ++c2) {
            const int rv = (c2 * 16 + m16) & 7;
            vf[0][c2] = *(const bf16x8*)(Vbuf + (c2 * 16 + m16) * 64 + ((g ^ rv) << 3));
            vf[1][c2] = *(const bf16x8*)(Vbuf + (c2 * 16 + m16) * 64 + (((4 + g) ^ rv) << 3));
        }

        // exp2 (folded scale), causal mask on diag tile (ALL waves), pack
        const bool maskT = (u == nt0 - 1) || (u == 32);
        uint32_t pk[4][2];
#pragma unroll
        for (int c = 0; c < 4; ++c) {
            float p[4];
#pragma unroll
            for (int r = 0; r < 4; ++r) {
                float v = exp2f(sc[c][r] * kSc);
                if (maskT && (kv0 + c * 16 + g * 4 + r > qrow)) v = 0.f;
                p[r] = v;
            }
            ps += (p[0] + p[1]) + (p[2] + p[3]);
            pk[c][0] = cvtpk(p[0], p[1]);
            pk[c][1] = cvtpk(p[2], p[3]);
        }

        // permlane redistribution: P^T fragments -> P A-fragments (no LDS)
        bf16x8 pf[2];
#pragma unroll
        for (int ks = 0; ks < 2; ++ks) {
            uint32_t ylo = pk[2 * ks][0], zlo = pk[2 * ks + 1][0];
            ps32(ylo, zlo); ps16(ylo, zlo);
            uint32_t yhi = pk[2 * ks][1], zhi = pk[2 * ks + 1][1];
            ps32(yhi, zhi); ps16(yhi, zhi);
            union { uint32_t u[4]; bf16x8 v; } fu;
            fu.u[0] = ylo; fu.u[1] = yhi; fu.u[2] = zlo; fu.u[3] = zhi;
            pf[ks] = fu.v;
        }

        // O += P V
        __builtin_amdgcn_s_setprio(1);
#pragma unroll
        for (int c2 = 0; c2 < 4; ++c2) {
            o[c2] = __builtin_amdgcn_mfma_f32_16x16x32_bf16(pf[0], vf[0][c2], o[c2], 0, 0, 0);
            o[c2] = __builtin_amdgcn_mfma_f32_16x16x32_bf16(pf[1], vf[1][c2], o[c2], 0, 0, 0);
        }
        __builtin_amdgcn_s_setprio(0);
    }

    // phase-1 epilogue: q-tile 31-j
    {
        float s = ps;
        s += __shfl_xor(s, 16);
        s += __shfl_xor(s, 32);
        const float inv = 1.f / s;
        float lrq[4];
#pragma unroll
        for (int r = 0; r < 4; ++r)
            lrq[r] = __shfl(inv, g * 4 + r);
#pragma unroll
        for (int c2 = 0; c2 < 4; ++c2)
#pragma unroll
            for (int r = 0; r < 4; ++r) {
                const int orow = (31 - j) * 64 + wid * 16 + g * 4 + r;
                const int ocol = h * DK_ + c2 * 16 + m16;
                O[((size_t)(b * S_ + orow)) * D_ + ocol] = f2bf(o[c2][r] * lrq[r]);
            }
    }
}

// ---------------- host launcher ----------------
extern "C" void kernel_launch(void* const* d_in, const int* in_sizes, int n_in,
                              void* d_out, int out_size, void* d_ws, size_t ws_size,
                              hipStream_t stream) {
    (void)in_sizes; (void)n_in; (void)out_size; (void)ws_size;
    const float* x   = (const float*)d_in[0];
    const float* Wq  = (const float*)d_in[1];
    const float* Wk  = (const float*)d_in[2];
    const float* Wv  = (const float*)d_in[3];
    const float* Wo  = (const float*)d_in[4];
    const int*   tok = (const int*)d_in[5];

    char* ws = (char*)d_ws;
    const size_t MB = 1u << 20;
    unsigned short* xb  = (unsigned short*)(ws + 0 * MB);   // 8 MB  [4096][1024] bf16
    unsigned short* wqb = (unsigned short*)(ws + 8 * MB);   // 2 MB each
    unsigned short* wkb = (unsigned short*)(ws + 10 * MB);
    unsigned short* wvb = (unsigned short*)(ws + 12 * MB);
    unsigned short* wob = (unsigned short*)(ws + 14 * MB);
    unsigned short* qh  = (unsigned short*)(ws + 16 * MB);  // 8 MB  [bh][s][64]
    unsigned short* kh  = (unsigned short*)(ws + 24 * MB);
    unsigned short* vh  = (unsigned short*)(ws + 32 * MB);  // [bh][64][2048] (V^T)
    unsigned short* ao  = (unsigned short*)(ws + 40 * MB);  // 8 MB  [b][s][1024]

    // 1) convert inputs to bf16 (2 launches)
    k_f32_to_bf16<<<4096, 256, 0, stream>>>(x, xb, (B_ * S_ * D_) / 4);
    k_wconv<<<dim3(1024, 4), 256, 0, stream>>>(Wq, Wk, Wv, Wo, wqb, wkb, wvb, wob);

    // 2) fused QKV projection -> head layout bf16 (V transposed)
    k_gemm_bt<0><<<dim3(32, 8, 3), 256, 0, stream>>>(
        xb, wqb, wkb, wvb, qh, kh, vh, B_ * S_, D_, D_);

    // 3) RoPE in place on Q,K
    k_rope_inplace<<<2048, 256, 0, stream>>>(qh, kh, tok);

    // 4) causal flash attention -> [b][s][e] bf16
    k_fattn8<<<dim3(512), 256, 0, stream>>>(qh, kh, vh, ao);

    // 5) output projection -> f32 d_out
    k_gemm_bt<1><<<dim3(32, 8, 1), 256, 0, stream>>>(
        ao, wob, wob, wob, d_out, d_out, d_out, B_ * S_, D_, D_);
}

// Round 11
// 127.025 us; speedup vs baseline: 1.0112x; 1.0112x over previous
//
#include <hip/hip_runtime.h>
#include <stdint.h>

#define B_  2
#define S_  2048
#define D_  1024
#define H_  16
#define DK_ 64

using bf16x8 = __attribute__((ext_vector_type(8))) short;
using f32x4  = __attribute__((ext_vector_type(4))) float;

__device__ __forceinline__ unsigned short f2bf(float f) {
    union { float f; uint32_t u; } v; v.f = f;
    uint32_t r = v.u + 0x7FFFu + ((v.u >> 16) & 1u);
    return (unsigned short)(r >> 16);
}

// pack two f32 -> one u32 of two bf16 (low = s0), RNE in HW
__device__ __forceinline__ uint32_t cvtpk(float lo, float hi) {
    uint32_t r;
    asm("v_cvt_pk_bf16_f32 %0, %1, %2" : "=v"(r) : "v"(lo), "v"(hi));
    return r;
}
// a' = {a(0-31), b(0-31)} ; b' = {a(32-63), b(32-63)}
__device__ __forceinline__ void ps32(uint32_t& a, uint32_t& b) {
    asm volatile("v_permlane32_swap_b32 %0, %1" : "+v"(a), "+v"(b));
}
// 16-lane rows: odd rows of a <-> even rows of b
__device__ __forceinline__ void ps16(uint32_t& a, uint32_t& b) {
    asm volatile("v_permlane16_swap_b32 %0, %1" : "+v"(a), "+v"(b));
}

// async global->LDS, 16B per lane; LDS dest is wave-uniform base + lane*16
#define GLD16(G, L) __builtin_amdgcn_global_load_lds( \
    (const __attribute__((address_space(1))) void*)(const void*)(G), \
    (__attribute__((address_space(3))) void*)(void*)(L), 16, 0, 0)

// ---------------- fp32 -> bf16 convert (vectorized) ----------------
__global__ __launch_bounds__(256) void k_f32_to_bf16(const float* __restrict__ src,
                                                     unsigned short* __restrict__ dst,
                                                     int n4) {
    int i = blockIdx.x * 256 + threadIdx.x;
    if (i >= n4) return;
    float4 v = ((const float4*)src)[i];
    union { unsigned short u[4]; uint2 d; } o;
    o.u[0] = f2bf(v.x); o.u[1] = f2bf(v.y); o.u[2] = f2bf(v.z); o.u[3] = f2bf(v.w);
    ((uint2*)dst)[i] = o.d;
}

// fused 4-weight convert: grid (1024, 4)
__global__ __launch_bounds__(256) void k_wconv(
    const float* __restrict__ s0, const float* __restrict__ s1,
    const float* __restrict__ s2, const float* __restrict__ s3,
    unsigned short* __restrict__ d0, unsigned short* __restrict__ d1,
    unsigned short* __restrict__ d2, unsigned short* __restrict__ d3) {
    const int w = blockIdx.y;
    const float* s = w == 0 ? s0 : w == 1 ? s1 : w == 2 ? s2 : s3;
    unsigned short* d = w == 0 ? d0 : w == 1 ? d1 : w == 2 ? d2 : d3;
    int i = blockIdx.x * 256 + threadIdx.x;
    float4 v = ((const float4*)s)[i];
    union { unsigned short u[4]; uint2 dd; } o;
    o.u[0] = f2bf(v.x); o.u[1] = f2bf(v.y); o.u[2] = f2bf(v.z); o.u[3] = f2bf(v.w);
    ((uint2*)d)[i] = o.dd;
}

// ---------------- GEMM: C[m][n] = sum_k A[m][k] * W[n][k]  (B^T input) ------
// conflict-free XOR swizzle (both-sides) + 2-phase prefetch (round-8 proven)
template<int MODE>
__global__ __launch_bounds__(256) void k_gemm_bt(
    const unsigned short* __restrict__ A,
    const unsigned short* __restrict__ W0,
    const unsigned short* __restrict__ W1,
    const unsigned short* __restrict__ W2,
    void* __restrict__ C0, void* __restrict__ C1, void* __restrict__ C2,
    int M, int N, int K)
{
    __shared__ __align__(16) unsigned short As[2][128 * 32];
    __shared__ __align__(16) unsigned short Bs[2][128 * 32];

    const int tid  = threadIdx.x;
    const int wid  = tid >> 6, lane = tid & 63;
    const int m16  = lane & 15, g = lane >> 4;
    const int m0   = blockIdx.x * 128, n0 = blockIdx.y * 128;
    const unsigned short* Wm = blockIdx.z == 0 ? W0 : (blockIdx.z == 1 ? W1 : W2);
    void* Cm = blockIdx.z == 0 ? C0 : (blockIdx.z == 1 ? C1 : C2);

    const int wm = (wid >> 1) * 64, wn = (wid & 1) * 64;
    const int srow = lane >> 2;
    const int scol = ((lane & 3) ^ ((lane >> 3) & 3)) * 8;
    const int sw8  = (m16 >> 1) & 3;

    const f32x4 fz = {0.f, 0.f, 0.f, 0.f};
    f32x4 acc[4][4];
#pragma unroll
    for (int i = 0; i < 4; ++i)
#pragma unroll
        for (int j = 0; j < 4; ++j) acc[i][j] = fz;

#pragma unroll
    for (int c = 0; c < 2; ++c) {
        const int chunk = wid * 2 + c;
        const int row   = chunk * 16 + srow;
        GLD16(A  + (size_t)(m0 + row) * K + scol, &As[0][chunk * 512]);
        GLD16(Wm + (size_t)(n0 + row) * K + scol, &Bs[0][chunk * 512]);
    }
    __syncthreads();

    int buf = 0;
    for (int k0 = 0; k0 < K; k0 += 32) {
        if (k0 + 32 < K) {
#pragma unroll
            for (int c = 0; c < 2; ++c) {
                const int chunk = wid * 2 + c;
                const int row   = chunk * 16 + srow;
                GLD16(A  + (size_t)(m0 + row) * K + k0 + 32 + scol, &As[buf ^ 1][chunk * 512]);
                GLD16(Wm + (size_t)(n0 + row) * K + k0 + 32 + scol, &Bs[buf ^ 1][chunk * 512]);
            }
        }
        bf16x8 af[4], bf[4];
#pragma unroll
        for (int i = 0; i < 4; ++i)
            af[i] = *(const bf16x8*)(&As[buf][(wm + i * 16 + m16) * 32 + ((g ^ sw8) * 8)]);
#pragma unroll
        for (int j = 0; j < 4; ++j)
            bf[j] = *(const bf16x8*)(&Bs[buf][(wn + j * 16 + m16) * 32 + ((g ^ sw8) * 8)]);
#pragma unroll
        for (int i = 0; i < 4; ++i)
#pragma unroll
            for (int j = 0; j < 4; ++j)
                acc[i][j] = __builtin_amdgcn_mfma_f32_16x16x32_bf16(af[i], bf[j], acc[i][j], 0, 0, 0);
        __syncthreads();
        buf ^= 1;
    }

#pragma unroll
    for (int i = 0; i < 4; ++i) {
#pragma unroll
        for (int j = 0; j < 4; ++j) {
#pragma unroll
            for (int r = 0; r < 4; ++r) {
                const int row = m0 + wm + i * 16 + g * 4 + r;
                const int col = n0 + wn + j * 16 + m16;
                const float val = acc[i][j][r];
                if (MODE == 1) {
                    ((float*)Cm)[(size_t)row * N + col] = val;
                } else {
                    const int b = row >> 11, s = row & (S_ - 1);
                    const int h = col >> 6,  dk = col & (DK_ - 1);
                    size_t idx;
                    if (blockIdx.z == 2)   // V: transposed [bh][dk][s]
                        idx = ((size_t)((b * H_ + h) * DK_ + dk)) * S_ + s;
                    else                   // Q,K: [bh][s][dk]
                        idx = ((size_t)((b * H_ + h) * S_ + s)) * DK_ + dk;
                    ((unsigned short*)Cm)[idx] = f2bf(val);
                }
            }
        }
    }
}

// ---------------- RoPE in place on [bh][s][dk] bf16 buffers ----------------
__global__ __launch_bounds__(256) void k_rope_inplace(
    unsigned short* __restrict__ qh, unsigned short* __restrict__ kh,
    const int* __restrict__ tok)
{
    const int idx = blockIdx.x * 256 + threadIdx.x;
    const int c = idx & 7;
    const int s = (idx >> 3) & (S_ - 1);
    const int b = idx >> 18;
    const size_t off = (size_t)idx * 8;

    const float pos = (float)tok[b * S_ + s];
    float cs[4], sn[4];
#pragma unroll
    for (int i = 0; i < 4; ++i) {
        const int p = c * 4 + i;
        const float inv = exp2f((float)(-2 * p) * (13.287712379549449f / 64.f));
        sincosf(pos * inv, &sn[i], &cs[i]);
    }
    bf16x8 qv = *(bf16x8*)(qh + off);
    bf16x8 kv = *(bf16x8*)(kh + off);
    bf16x8 qo, ko;
#pragma unroll
    for (int i = 0; i < 4; ++i) {
        union { uint32_t u; float f; } q1{(uint32_t)(unsigned short)qv[2*i] << 16};
        union { uint32_t u; float f; } q2{(uint32_t)(unsigned short)qv[2*i+1] << 16};
        qo[2 * i]     = (short)f2bf(q1.f * cs[i] - q2.f * sn[i]);
        qo[2 * i + 1] = (short)f2bf(q1.f * sn[i] + q2.f * cs[i]);
        union { uint32_t u; float f; } k1{(uint32_t)(unsigned short)kv[2*i] << 16};
        union { uint32_t u; float f; } k2{(uint32_t)(unsigned short)kv[2*i+1] << 16};
        ko[2 * i]     = (short)f2bf(k1.f * cs[i] - k2.f * sn[i]);
        ko[2 * i + 1] = (short)f2bf(k1.f * sn[i] + k2.f * cs[i]);
    }
    *(bf16x8*)(qh + off) = qo;
    *(bf16x8*)(kh + off) = ko;
}

// ---------------- causal flash attention v9 ----------------
// v6 structure (16-row waves, uniform fold j/31-j, permlane P, dbuf +
// __syncthreads) widened to 2-TILE INTERVALS: each barrier interval stages
// and computes a 128-kv slab (two 64-kv tiles A,B with independent
// QK->softmax->PV chains -> 2x ILP per wave). 17 intervals for every j
// (ceil((j+1)/2) + ceil((32-j)/2) = 17). LDS 64 KB, 2 blocks/CU.
#define TILE_PF(T, diag, kvb, pfOut)                                         \
  {                                                                          \
    f32x4 sc_[4];                                                            \
    __builtin_amdgcn_s_setprio(1);                                           \
    _Pragma("unroll")                                                        \
    for (int c = 0; c < 4; ++c) {                                            \
      const int row_ = (T) * 64 + c * 16 + m16, rr_ = row_ & 7;              \
      bf16x8 kf0 = *(const bf16x8*)(Kbuf + row_ * 64 + ((g ^ rr_) << 3));    \
      bf16x8 kf1 = *(const bf16x8*)(Kbuf + row_ * 64 + (((4 + g) ^ rr_) << 3)); \
      f32x4 z_ = fz;                                                         \
      z_ = __builtin_amdgcn_mfma_f32_16x16x32_bf16(kf0, qf[0], z_, 0, 0, 0); \
      z_ = __builtin_amdgcn_mfma_f32_16x16x32_bf16(kf1, qf[1], z_, 0, 0, 0); \
      sc_[c] = z_;                                                           \
    }                                                                        \
    __builtin_amdgcn_s_setprio(0);                                           \
    uint32_t pk_[4][2];                                                      \
    _Pragma("unroll")                                                        \
    for (int c = 0; c < 4; ++c) {                                            \
      float p_[4];                                                           \
      _Pragma("unroll")                                                      \
      for (int r = 0; r < 4; ++r) {                                          \
        float v_ = exp2f(sc_[c][r] * kSc);                                   \
        if ((diag) && ((kvb) + c * 16 + g * 4 + r > qrow)) v_ = 0.f;         \
        p_[r] = v_;                                                          \
      }                                                                      \
      ps += (p_[0] + p_[1]) + (p_[2] + p_[3]);                               \
      pk_[c][0] = cvtpk(p_[0], p_[1]);                                       \
      pk_[c][1] = cvtpk(p_[2], p_[3]);                                       \
    }                                                                        \
    _Pragma("unroll")                                                        \
    for (int ks = 0; ks < 2; ++ks) {                                         \
      uint32_t ylo = pk_[2 * ks][0], zlo = pk_[2 * ks + 1][0];               \
      ps32(ylo, zlo); ps16(ylo, zlo);                                        \
      uint32_t yhi = pk_[2 * ks][1], zhi = pk_[2 * ks + 1][1];               \
      ps32(yhi, zhi); ps16(yhi, zhi);                                        \
      union { uint32_t u[4]; bf16x8 v; } fu_;                                \
      fu_.u[0] = ylo; fu_.u[1] = yhi; fu_.u[2] = zlo; fu_.u[3] = zhi;        \
      pfOut[ks] = fu_.v;                                                     \
    }                                                                        \
  }

#define TILE_PV(T, pfIn)                                                     \
  {                                                                          \
    __builtin_amdgcn_s_setprio(1);                                           \
    _Pragma("unroll")                                                        \
    for (int c2 = 0; c2 < 4; ++c2) {                                         \
      const int dv_ = c2 * 16 + m16, rv_ = dv_ & 7;                          \
      bf16x8 v0 = *(const bf16x8*)(Vbuf + dv_ * 128 + ((((T) * 8 + g) ^ rv_) << 3)); \
      bf16x8 v1 = *(const bf16x8*)(Vbuf + dv_ * 128 + ((((T) * 8 + 4 + g) ^ rv_) << 3)); \
      o[c2] = __builtin_amdgcn_mfma_f32_16x16x32_bf16(pfIn[0], v0, o[c2], 0, 0, 0); \
      o[c2] = __builtin_amdgcn_mfma_f32_16x16x32_bf16(pfIn[1], v1, o[c2], 0, 0, 0); \
    }                                                                        \
    __builtin_amdgcn_s_setprio(0);                                           \
  }

#define STAGE_KV(bd, kb)                                                     \
  {                                                                          \
    _Pragma("unroll")                                                        \
    for (int c = 0; c < 4; ++c) {                                            \
      const int chunk_ = wid * 4 + c;                                        \
      const int krow_ = chunk_ * 8 + kr8;                                    \
      GLD16(Kb + (size_t)((kb) + krow_) * DK_ + kslot * 8, &Ks[bd][chunk_ * 512]); \
      const int dv_ = chunk_ * 4 + vr4;                                      \
      GLD16(Vb + (size_t)dv_ * S_ + (kb) + ((vs0 ^ (dv_ & 7)) * 8), &Vs[bd][chunk_ * 512]); \
    }                                                                        \
  }

__global__ __launch_bounds__(256, 2) void k_fattn9(
    const unsigned short* __restrict__ Q,   // [bh][s][64]
    const unsigned short* __restrict__ K,   // [bh][s][64]
    const unsigned short* __restrict__ Vt,  // [bh][64][2048]
    unsigned short* __restrict__ O)         // [b][s][1024] bf16
{
    __shared__ __align__(16) unsigned short Ks[2][128 * 64];  // 16 KB each
    __shared__ __align__(16) unsigned short Vs[2][64 * 128];  // [dv][kv128]

    const int tid = threadIdx.x, wid = tid >> 6, lane = tid & 63;
    const int m16 = lane & 15, g = lane >> 4;
    const int bh = blockIdx.x & 31;
    const int j  = blockIdx.x >> 5;                     // 0..15
    const int b = bh >> 4, h = bh & 15;
    const unsigned short* Qb = Q  + (size_t)bh * S_ * DK_;
    const unsigned short* Kb = K  + (size_t)bh * S_ * DK_;
    const unsigned short* Vb = Vt + (size_t)bh * DK_ * S_;

    // staging lane constants
    const int kr8 = lane >> 3;           // K: row within 8-row chunk
    const int kslot = (lane & 7) ^ kr8;  // K: pre-swizzled source slot
    const int vr4 = lane >> 4;           // V: dv row within 4-row chunk
    const int vs0 = lane & 15;           // V: dest slot (src col = slot^(dv&7))

    const f32x4 fz = {0.f, 0.f, 0.f, 0.f};
    const float kSc = 0.125f * 1.4426950408889634f;   // 1/sqrt(DK) * log2(e)

    // prologue: stage phase-0 interval 0 (kv 0..127) into buf 0
    STAGE_KV(0, 0)
    __syncthreads();

    int buf = 0;
#pragma unroll
    for (int ph = 0; ph < 2; ++ph) {
        const int qi = ph ? 31 - j : j;
        const int qw0 = qi * 64 + wid * 16;             // this wave's 16 rows
        const int qrow = qw0 + m16;

        bf16x8 qf[2];
        {
            const unsigned short* qp = Qb + (size_t)qrow * DK_ + g * 8;
            qf[0] = *(const bf16x8*)(qp);
            qf[1] = *(const bf16x8*)(qp + 32);
        }

        f32x4 o[4];
#pragma unroll
        for (int i = 0; i < 4; ++i) o[i] = fz;
        float ps = 0.f;

        const int nt = qi + 1;                // 64-kv tiles this phase
        const int nI = (nt + 1) >> 1;         // 128-kv intervals
        for (int i = 0; i < nI; ++i) {
            // stage next interval (or phase-1 interval 0 at fold boundary)
            int nkb = -1;
            if (i + 1 < nI)      nkb = (i + 1) * 128;
            else if (ph == 0)    nkb = 0;
            if (nkb >= 0) STAGE_KV(buf ^ 1, nkb)

            const unsigned short* Kbuf = Ks[buf];
            const unsigned short* Vbuf = Vs[buf];
            const int kbA = i * 128;
            const bool vB = (2 * i + 1 < nt);
            const bool dA = (2 * i == nt - 1);
            const bool dB = (2 * i + 1 == nt - 1);

            bf16x8 pfA[2], pfB[2];
            TILE_PF(0, dA, kbA, pfA)
            if (vB) { TILE_PF(1, dB, kbA + 64, pfB) }
            TILE_PV(0, pfA)
            if (vB) { TILE_PV(1, pfB) }

            __syncthreads();             // next interval staged; buf flip safe
            buf ^= 1;
        }

        // epilogue: denominator at lanes m16 = q; reduce over 4 g-copies
        float s = ps;
        s += __shfl_xor(s, 16);
        s += __shfl_xor(s, 32);
        const float inv = 1.f / s;
        float lrq[4];
#pragma unroll
        for (int r = 0; r < 4; ++r)
            lrq[r] = __shfl(inv, g * 4 + r);
#pragma unroll
        for (int c2 = 0; c2 < 4; ++c2)
#pragma unroll
            for (int r = 0; r < 4; ++r) {
                const int orow = qw0 + g * 4 + r;
                const int ocol = h * DK_ + c2 * 16 + m16;
                O[((size_t)(b * S_ + orow)) * D_ + ocol] = f2bf(o[c2][r] * lrq[r]);
            }
    }
}

// ---------------- host launcher ----------------
extern "C" void kernel_launch(void* const* d_in, const int* in_sizes, int n_in,
                              void* d_out, int out_size, void* d_ws, size_t ws_size,
                              hipStream_t stream) {
    (void)in_sizes; (void)n_in; (void)out_size; (void)ws_size;
    const float* x   = (const float*)d_in[0];
    const float* Wq  = (const float*)d_in[1];
    const float* Wk  = (const float*)d_in[2];
    const float* Wv  = (const float*)d_in[3];
    const float* Wo  = (const float*)d_in[4];
    const int*   tok = (const int*)d_in[5];

    char* ws = (char*)d_ws;
    const size_t MB = 1u << 20;
    unsigned short* xb  = (unsigned short*)(ws + 0 * MB);   // 8 MB  [4096][1024] bf16
    unsigned short* wqb = (unsigned short*)(ws + 8 * MB);   // 2 MB each
    unsigned short* wkb = (unsigned short*)(ws + 10 * MB);
    unsigned short* wvb = (unsigned short*)(ws + 12 * MB);
    unsigned short* wob = (unsigned short*)(ws + 14 * MB);
    unsigned short* qh  = (unsigned short*)(ws + 16 * MB);  // 8 MB  [bh][s][64]
    unsigned short* kh  = (unsigned short*)(ws + 24 * MB);
    unsigned short* vh  = (unsigned short*)(ws + 32 * MB);  // [bh][64][2048] (V^T)
    unsigned short* ao  = (unsigned short*)(ws + 40 * MB);  // 8 MB  [b][s][1024]

    // 1) convert inputs to bf16 (2 launches)
    k_f32_to_bf16<<<4096, 256, 0, stream>>>(x, xb, (B_ * S_ * D_) / 4);
    k_wconv<<<dim3(1024, 4), 256, 0, stream>>>(Wq, Wk, Wv, Wo, wqb, wkb, wvb, wob);

    // 2) fused QKV projection -> head layout bf16 (V transposed)
    k_gemm_bt<0><<<dim3(32, 8, 3), 256, 0, stream>>>(
        xb, wqb, wkb, wvb, qh, kh, vh, B_ * S_, D_, D_);

    // 3) RoPE in place on Q,K
    k_rope_inplace<<<2048, 256, 0, stream>>>(qh, kh, tok);

    // 4) causal flash attention -> [b][s][e] bf16
    k_fattn9<<<dim3(512), 256, 0, stream>>>(qh, kh, vh, ao);

    // 5) output projection -> f32 d_out
    k_gemm_bt<1><<<dim3(32, 8, 1), 256, 0, stream>>>(
        ao, wob, wob, wob, d_out, d_out, d_out, B_ * S_, D_, D_);
}